// Round 8
// baseline (494.181 us; speedup 1.0000x reference)
//
#include <hip/hip_runtime.h>
#include <stdint.h>

#define BDIM 32
#define CDIM 32
#define LDIM 1024
#define VDIM 4096
#define BCL (BDIM*CDIM*LDIM)

// ---------------------------------------------------------------- init
__global__ void init_kernel(const float* __restrict__ f, const float* __restrict__ emb,
                            float* __restrict__ f_rest, float* __restrict__ f_hat,
                            float* __restrict__ e_sq, float* __restrict__ loss_acc,
                            unsigned* __restrict__ done_ctr,
                            unsigned long long* __restrict__ keys, int nkeys) {
    int i = blockIdx.x * blockDim.x + threadIdx.x;
    if (i < BCL) { f_rest[i] = f[i]; f_hat[i] = 0.0f; }
    if (i < VDIM) {
        const float4* e4 = (const float4*)(emb + (size_t)i * CDIM);
        float s = 0.f;
#pragma unroll
        for (int k = 0; k < 8; ++k) {
            float4 v = e4[k];
            s += v.x*v.x; s += v.y*v.y; s += v.z*v.z; s += v.w*v.w;
        }
        e_sq[i] = s;
    }
    if (i < nkeys) keys[i] = ~0ull;
    if (i == 0) { *loss_acc = 0.f; *done_ctr = 0u; }
}

// ---------------------------------------------------------------- VQ argmin: lane-per-query scan
// LESSONS (rounds 1-7): register-tiled GEMM structures with large per-thread accumulator
// arrays (acc[64]/acc[128]) are consistently mangled by the allocator (scratch spill /
// AGPR parking / low occupancy) -- best 154us vs 55us FMA floor. Round-1's lane-per-query
// had a scalar accumulator (allocator-proof) but died on serialized wave-uniform s_loads.
// THIS kernel combines them: one query PAIR per lane (z in 64 read-only regs), code chunk
// staged in LDS once, read via wave-uniform BROADCAST ds_read_b128 (same-address = conflict
// free by HW rule; no swizzle; no k$). Per code per wave: 9 LDS reads vs 64 FMA + ~10 VALU
// -> ~87% of VALU issue is useful FMA. Argmin state = (bd,bv) scalars; NO reduction;
// 2 atomicMin per lane at kernel end. One __syncthreads per block total.
__global__ __launch_bounds__(256) void vq_scan(
    const float* __restrict__ f_rest, const float* __restrict__ emb,
    const float* __restrict__ e_sq, unsigned long long* __restrict__ keys,
    int lpl, int s, int NQ, int VC, int vchunks)
{
    const int pl = 1 << lpl;
    const int t  = threadIdx.x;
    const int qg = blockIdx.x / vchunks;    // 512-query group
    const int vc = blockIdx.x % vchunks;
    const int vb = vc * VC;

    __shared__ __align__(16) float e_ls[256 * 32];   // up to 256 codes x 32 ch (32 KB)
    __shared__ float esq_ls[256];

    // ---- stage code chunk (linear, coalesced; VC*8 float4s over 256 threads)
    {
        const float4* src = (const float4*)emb + (size_t)vb * 8;
        float4* dst = (float4*)e_ls;
        for (int x = t; x < VC * 8; x += 256) dst[x] = src[x];
        for (int v = t; v < VC; v += 256) esq_ls[v] = e_sq[vb + v];
    }

    // ---- load this lane's two query vectors into registers
    const int lane = t & 63;
    const int wv   = t >> 6;
    const int q0 = qg * 512 + wv * 128 + lane;
    const int q1 = q0 + 64;
    const int qc0 = (q0 < NQ) ? q0 : NQ - 1;
    const int qc1 = (q1 < NQ) ? q1 : NQ - 1;

    float z0[32], z1[32];
    {
        int b0 = qc0 >> lpl, j0 = qc0 & (pl - 1);
        int b1 = qc1 >> lpl, j1 = qc1 & (pl - 1);
        if (pl == LDIM) {
            const float* p0 = f_rest + b0 * (CDIM * LDIM) + j0;
            const float* p1 = f_rest + b1 * (CDIM * LDIM) + j1;
#pragma unroll
            for (int c = 0; c < 32; ++c) { z0[c] = p0[c * LDIM]; z1[c] = p1[c * LDIM]; }
        } else {
            int col0 = j0 * s + (s >> 1) - 1;
            int col1 = j1 * s + (s >> 1) - 1;
            const float* p0 = f_rest + b0 * (CDIM * LDIM) + col0;
            const float* p1 = f_rest + b1 * (CDIM * LDIM) + col1;
#pragma unroll
            for (int c = 0; c < 32; ++c) {
                z0[c] = 0.5f * (p0[c * LDIM] + p0[c * LDIM + 1]);
                z1[c] = 0.5f * (p1[c * LDIM] + p1[c * LDIM + 1]);
            }
        }
    }

    __syncthreads();

    // ---- scan: biased distance d' = e_sq - 2*dot (zz const per query);
    // dot chain order c=0..31 sequential (bit-identical to prior passing kernels).
    float bd0 = 3.4e38f, bd1 = 3.4e38f;
    int bv0 = 0, bv1 = 0;

#pragma unroll 2
    for (int v = 0; v < VC; ++v) {
        const float4* er = (const float4*)&e_ls[v * 32];
        float4 ea = er[0], eb = er[1], ec = er[2], ed = er[3];
        float4 ee = er[4], ef = er[5], eg = er[6], eh = er[7];
        float es = esq_ls[v];

        float d0, d1;
        {
            float a0 = z0[0] * ea.x, a1 = z1[0] * ea.x;
            a0 = fmaf(z0[1], ea.y, a0);  a1 = fmaf(z1[1], ea.y, a1);
            a0 = fmaf(z0[2], ea.z, a0);  a1 = fmaf(z1[2], ea.z, a1);
            a0 = fmaf(z0[3], ea.w, a0);  a1 = fmaf(z1[3], ea.w, a1);
            a0 = fmaf(z0[4], eb.x, a0);  a1 = fmaf(z1[4], eb.x, a1);
            a0 = fmaf(z0[5], eb.y, a0);  a1 = fmaf(z1[5], eb.y, a1);
            a0 = fmaf(z0[6], eb.z, a0);  a1 = fmaf(z1[6], eb.z, a1);
            a0 = fmaf(z0[7], eb.w, a0);  a1 = fmaf(z1[7], eb.w, a1);
            a0 = fmaf(z0[8], ec.x, a0);  a1 = fmaf(z1[8], ec.x, a1);
            a0 = fmaf(z0[9], ec.y, a0);  a1 = fmaf(z1[9], ec.y, a1);
            a0 = fmaf(z0[10], ec.z, a0); a1 = fmaf(z1[10], ec.z, a1);
            a0 = fmaf(z0[11], ec.w, a0); a1 = fmaf(z1[11], ec.w, a1);
            a0 = fmaf(z0[12], ed.x, a0); a1 = fmaf(z1[12], ed.x, a1);
            a0 = fmaf(z0[13], ed.y, a0); a1 = fmaf(z1[13], ed.y, a1);
            a0 = fmaf(z0[14], ed.z, a0); a1 = fmaf(z1[14], ed.z, a1);
            a0 = fmaf(z0[15], ed.w, a0); a1 = fmaf(z1[15], ed.w, a1);
            a0 = fmaf(z0[16], ee.x, a0); a1 = fmaf(z1[16], ee.x, a1);
            a0 = fmaf(z0[17], ee.y, a0); a1 = fmaf(z1[17], ee.y, a1);
            a0 = fmaf(z0[18], ee.z, a0); a1 = fmaf(z1[18], ee.z, a1);
            a0 = fmaf(z0[19], ee.w, a0); a1 = fmaf(z1[19], ee.w, a1);
            a0 = fmaf(z0[20], ef.x, a0); a1 = fmaf(z1[20], ef.x, a1);
            a0 = fmaf(z0[21], ef.y, a0); a1 = fmaf(z1[21], ef.y, a1);
            a0 = fmaf(z0[22], ef.z, a0); a1 = fmaf(z1[22], ef.z, a1);
            a0 = fmaf(z0[23], ef.w, a0); a1 = fmaf(z1[23], ef.w, a1);
            a0 = fmaf(z0[24], eg.x, a0); a1 = fmaf(z1[24], eg.x, a1);
            a0 = fmaf(z0[25], eg.y, a0); a1 = fmaf(z1[25], eg.y, a1);
            a0 = fmaf(z0[26], eg.z, a0); a1 = fmaf(z1[26], eg.z, a1);
            a0 = fmaf(z0[27], eg.w, a0); a1 = fmaf(z1[27], eg.w, a1);
            a0 = fmaf(z0[28], eh.x, a0); a1 = fmaf(z1[28], eh.x, a1);
            a0 = fmaf(z0[29], eh.y, a0); a1 = fmaf(z1[29], eh.y, a1);
            a0 = fmaf(z0[30], eh.z, a0); a1 = fmaf(z1[30], eh.z, a1);
            a0 = fmaf(z0[31], eh.w, a0); a1 = fmaf(z1[31], eh.w, a1);
            d0 = fmaf(a0, -2.0f, es);
            d1 = fmaf(a1, -2.0f, es);
        }
        int vg = vb + v;
        if (d0 < bd0) { bd0 = d0; bv0 = vg; }
        if (d1 < bd1) { bd1 = d1; bv1 = vg; }
    }

    if (q0 < NQ) {
        unsigned ud = __float_as_uint(bd0);
        ud = (ud & 0x80000000u) ? ~ud : (ud | 0x80000000u);
        atomicMin(&keys[q0], ((unsigned long long)ud << 32) | (unsigned)bv0);
    }
    if (q1 < NQ) {
        unsigned ud = __float_as_uint(bd1);
        ud = (ud & 0x80000000u) ? ~ud : (ud | 0x80000000u);
        atomicMin(&keys[q1], ((unsigned long long)ud << 32) | (unsigned)bv1);
    }
}

// ---------------------------------------------------------------- fused gather+upsample+phi+update+loss
// Also: resets the NEXT scale's key buffer (ping-pong, disjoint from the one it reads),
// and for the last scale finalizes the loss via a done-counter (drops final_kernel).
__global__ __launch_bounds__(256) void fuse_kernel(
    const float* __restrict__ f, const float* __restrict__ emb,
    const unsigned long long* __restrict__ keys,
    unsigned long long* __restrict__ keys_next, int nq_next,
    const float* __restrict__ w, const float* __restrict__ bias,
    float* __restrict__ f_rest, float* __restrict__ f_hat,
    float* __restrict__ loss_acc, unsigned* __restrict__ done_ctr,
    float* __restrict__ out_loss, int pl)
{
    const int t  = threadIdx.x;
    const int b  = blockIdx.y;
    const int l0 = blockIdx.x * 128;

    // reset next scale's keys (different buffer than 'keys'; safe to do immediately)
    if (keys_next) {
        int x = (b * gridDim.x + blockIdx.x) * 256 + t;
        if (x < nq_next) keys_next[x] = ~0ull;
    }

    __shared__ float w_s[3072];      // [o][i][k]
    __shared__ float b_s[32];
    __shared__ float hs[32 * 132];   // [i][130 (+pad)] : col x -> l = l0 - 1 + x
    __shared__ float red[4];

    for (int x = t; x < 3072; x += 256) w_s[x] = w[x];
    if (t < 32) b_s[t] = bias[t];

    if (t < 130) {
        int l = l0 - 1 + t;
        if (l < 0 || l >= LDIM) {
#pragma unroll
            for (int i = 0; i < 32; ++i) hs[i * 132 + t] = 0.f;
        } else {
            int lo, hi; float wg;
            if (pl == LDIM) { lo = l; hi = l; wg = 0.f; }
            else {
                float pos = (l + 0.5f) * ((float)pl / 1024.0f) - 0.5f;
                pos = fminf(fmaxf(pos, 0.f), (float)(pl - 1));
                lo = (int)floorf(pos);
                hi = min(lo + 1, pl - 1);
                wg = pos - (float)lo;
            }
            int v0 = (int)(keys[b * pl + lo] & 0xFFFFFFFFull);
            int v1 = (int)(keys[b * pl + hi] & 0xFFFFFFFFull);
            const float4* e0 = (const float4*)(emb + (size_t)v0 * 32);
            const float4* e1 = (const float4*)(emb + (size_t)v1 * 32);
            float om = 1.0f - wg;
#pragma unroll
            for (int i4 = 0; i4 < 8; ++i4) {
                float4 a = e0[i4]; float4 c = e1[i4];
                hs[(i4*4+0) * 132 + t] = a.x * om + c.x * wg;
                hs[(i4*4+1) * 132 + t] = a.y * om + c.y * wg;
                hs[(i4*4+2) * 132 + t] = a.z * om + c.z * wg;
                hs[(i4*4+3) * 132 + t] = a.w * om + c.w * wg;
            }
        }
    }
    __syncthreads();

    const int o  = t >> 3;        // output channel, fixed per thread (w reuse x16)
    const int lg = t & 7;         // 16 consecutive l's per thread
    const float* wrow = &w_s[o * 96];
    float acc[16];
#pragma unroll
    for (int u = 0; u < 16; ++u) acc[u] = 0.f;
    const int hbase = lg * 16;    // hs col for l = l0 + lg*16 - 1

    for (int i = 0; i < 32; ++i) {
        float w0 = wrow[i * 3 + 0], w1 = wrow[i * 3 + 1], w2 = wrow[i * 3 + 2];
        const float* hrow = &hs[i * 132 + hbase];
        float hw[18];
#pragma unroll
        for (int x = 0; x < 18; ++x) hw[x] = hrow[x];
#pragma unroll
        for (int u = 0; u < 16; ++u) {
            acc[u] = fmaf(w0, hw[u], acc[u]);
            acc[u] = fmaf(w1, hw[u + 1], acc[u]);
            acc[u] = fmaf(w2, hw[u + 2], acc[u]);
        }
    }

    float lsum = 0.f;
    const int gbase = (b * 32 + o) * LDIM + l0 + lg * 16;
#pragma unroll
    for (int u = 0; u < 16; ++u) {
        float hval = hs[o * 132 + lg * 16 + 1 + u];
        float y = acc[u] + b_s[o];
        float ph = 0.5f * hval + 0.5f * y;    // h*(1-RESI) + (conv+b)*RESI, RESI=0.5
        int gi = gbase + u;
        float fh = f_hat[gi] + ph;
        f_hat[gi] = fh;
        f_rest[gi] -= ph;
        float df = fh - f[gi];
        lsum = fmaf(df, df, lsum);
    }

#pragma unroll
    for (int off = 32; off > 0; off >>= 1) lsum += __shfl_down(lsum, off, 64);
    if ((t & 63) == 0) red[t >> 6] = lsum;
    __syncthreads();
    if (t == 0) {
        atomicAdd(loss_acc, red[0] + red[1] + red[2] + red[3]);
        if (out_loss) {
            __threadfence();
            unsigned old = atomicAdd(done_ctr, 1u);
            if (old == (unsigned)(gridDim.x * gridDim.y - 1)) {
                float lv = atomicAdd(loss_acc, 0.0f);   // coherent read after all adds
                *out_loss = lv * (1.25f / (6.0f * (float)BCL));
            }
        }
    }
}

// ---------------------------------------------------------------- launch
extern "C" void kernel_launch(void* const* d_in, const int* in_sizes, int n_in,
                              void* d_out, int out_size, void* d_ws, size_t ws_size,
                              hipStream_t stream)
{
    const float* f    = (const float*)d_in[0];
    const float* emb  = (const float*)d_in[1];
    const float* phiw = (const float*)d_in[2];
    const float* phib = (const float*)d_in[3];

    float* f_hat    = (float*)d_out;        // BCL floats
    float* out_loss = f_hat + BCL;          // +1 float

    const int pls[6]  = {1, 4, 16, 64, 256, 1024};
    const int lpls[6] = {0, 2, 4, 6, 8, 10};
    // vchunks: grid fill vs atomic count. blocks = ceil(NQ/512) * vch.
    // pl=1024: 64*16 = 1024 blocks (4/CU), VC=256 (single 32KB LDS subtile).
    const int vch[6]  = {64, 64, 64, 32, 16, 16};
    const int pidx[6] = {0, 0, 1, 2, 3, 3};          // PhiPartiallyShared static tick lookup

    char* ws = (char*)d_ws;
    float* f_rest             = (float*)ws;                            // 4 MB
    unsigned long long* keysA = (unsigned long long*)(ws + (size_t)BCL * 4);   // 256 KB

    // Ping-pong keys (A/B): fuse(si) reads one buffer and resets the other for si+1.
    // No hipMemsetAsync dispatches on the pp path. Fallback: single buffer + memsets.
    size_t need_pp = (size_t)BCL * 4 + (size_t)65536 * 8 + (size_t)VDIM * 4 + 64;
    bool pp = ws_size >= need_pp;
    unsigned long long* keysB = pp ? keysA + 32768 : keysA;
    size_t keys_bytes = pp ? (size_t)65536 * 8 : (size_t)32768 * 8;
    float* e_sq        = (float*)(ws + (size_t)BCL * 4 + keys_bytes);
    float* loss_acc    = e_sq + VDIM;
    unsigned* done_ctr = (unsigned*)(loss_acc + 1);

    init_kernel<<<dim3((BCL + 255) / 256), 256, 0, stream>>>(
        f, emb, f_rest, f_hat, e_sq, loss_acc, done_ctr, keysA, 32768);

    for (int si = 0; si < 6; ++si) {
        int pl = pls[si];
        int s  = LDIM / pl;
        int NQ = BDIM * pl;
        int qgroups = (NQ + 511) >> 9;
        int VC = VDIM / vch[si];
        unsigned long long* k  = (si & 1) ? keysB : keysA;
        unsigned long long* kn = (si < 5 && pp) ? ((si & 1) ? keysA : keysB) : nullptr;
        int nq_next = (si < 5) ? BDIM * pls[si + 1] : 0;
        if (!pp && si > 0) hipMemsetAsync(k, 0xFF, (size_t)NQ * 8, stream);
        vq_scan<<<dim3(qgroups * vch[si]), 256, 0, stream>>>(
            f_rest, emb, e_sq, k, lpls[si], s, NQ, VC, vch[si]);
        fuse_kernel<<<dim3(8, 32), 256, 0, stream>>>(
            f, emb, k, kn, nq_next,
            phiw + (size_t)pidx[si] * 3072, phib + (size_t)pidx[si] * 32,
            f_rest, f_hat, loss_acc, done_ctr,
            (si == 5) ? out_loss : nullptr, pl);
    }
}

// Round 9
// 442.974 us; speedup vs baseline: 1.1156x; 1.1156x over previous
//
#include <hip/hip_runtime.h>
#include <stdint.h>

#define BDIM 32
#define CDIM 32
#define LDIM 1024
#define VDIM 4096
#define BCL (BDIM*CDIM*LDIM)

// ---------------------------------------------------------------- init
__global__ void init_kernel(const float* __restrict__ f, const float* __restrict__ emb,
                            float* __restrict__ f_rest, float* __restrict__ f_hat,
                            float* __restrict__ e_sq, float* __restrict__ loss_acc,
                            unsigned* __restrict__ done_ctr,
                            unsigned long long* __restrict__ keys, int nkeys) {
    int i = blockIdx.x * blockDim.x + threadIdx.x;
    if (i < BCL) { f_rest[i] = f[i]; f_hat[i] = 0.0f; }
    if (i < VDIM) {
        const float4* e4 = (const float4*)(emb + (size_t)i * CDIM);
        float s = 0.f;
#pragma unroll
        for (int k = 0; k < 8; ++k) {
            float4 v = e4[k];
            s += v.x*v.x; s += v.y*v.y; s += v.z*v.z; s += v.w*v.w;
        }
        e_sq[i] = s;
    }
    if (i < nkeys) keys[i] = ~0ull;
    if (i == 0) { *loss_acc = 0.f; *done_ctr = 0u; }
}

// ---------------------------------------------------------------- VQ argmin: lane-per-query scan
// Round-8 structure (best: 132us): query PAIR per lane, code chunk in LDS read via
// wave-uniform broadcast ds_read_b128 (conflict-free), scalar argmin state, no reduction.
// Round-8 counter read: VGPR_Count=64 while z0+z1 alone need 64 -> compiler targeted
// 8 waves/SIMD and parked z in AGPRs; every FMA drags v_accvgpr_read (VALU 74% busy,
// only ~41% useful; 2x the 55us FMA floor = 132us observed).
// FIX: amdgpu_waves_per_eu(4) -> 128-reg budget (demand ~115). Occupancy is LDS/grid
// capped at 4 waves/SIMD anyway (33KB/block, 4 blocks/CU), so nothing is lost.
__global__ __attribute__((amdgpu_waves_per_eu(4))) __launch_bounds__(256) void vq_scan(
    const float* __restrict__ f_rest, const float* __restrict__ emb,
    const float* __restrict__ e_sq, unsigned long long* __restrict__ keys,
    int lpl, int s, int NQ, int VC, int vchunks)
{
    const int pl = 1 << lpl;
    const int t  = threadIdx.x;
    const int qg = blockIdx.x / vchunks;    // 512-query group
    const int vc = blockIdx.x % vchunks;
    const int vb = vc * VC;

    __shared__ __align__(16) float e_ls[256 * 32];   // up to 256 codes x 32 ch (32 KB)
    __shared__ float esq_ls[256];

    // ---- stage code chunk (linear, coalesced; VC*8 float4s over 256 threads)
    {
        const float4* src = (const float4*)emb + (size_t)vb * 8;
        float4* dst = (float4*)e_ls;
        for (int x = t; x < VC * 8; x += 256) dst[x] = src[x];
        for (int v = t; v < VC; v += 256) esq_ls[v] = e_sq[vb + v];
    }

    // ---- load this lane's two query vectors into registers (skip loads for dead lanes)
    const int lane = t & 63;
    const int wv   = t >> 6;
    const int q0 = qg * 512 + wv * 128 + lane;
    const int q1 = q0 + 64;

    float z0[32], z1[32];
#pragma unroll
    for (int c = 0; c < 32; ++c) { z0[c] = 0.f; z1[c] = 0.f; }
    {
        int b0 = (q0 < NQ ? q0 : 0) >> lpl, j0 = (q0 < NQ ? q0 : 0) & (pl - 1);
        int b1 = (q1 < NQ ? q1 : 0) >> lpl, j1 = (q1 < NQ ? q1 : 0) & (pl - 1);
        if (pl == LDIM) {
            const float* p0 = f_rest + b0 * (CDIM * LDIM) + j0;
            const float* p1 = f_rest + b1 * (CDIM * LDIM) + j1;
            if (q0 < NQ) {
#pragma unroll
                for (int c = 0; c < 32; ++c) z0[c] = p0[c * LDIM];
            }
            if (q1 < NQ) {
#pragma unroll
                for (int c = 0; c < 32; ++c) z1[c] = p1[c * LDIM];
            }
        } else {
            int col0 = j0 * s + (s >> 1) - 1;
            int col1 = j1 * s + (s >> 1) - 1;
            const float* p0 = f_rest + b0 * (CDIM * LDIM) + col0;
            const float* p1 = f_rest + b1 * (CDIM * LDIM) + col1;
            if (q0 < NQ) {
#pragma unroll
                for (int c = 0; c < 32; ++c) z0[c] = 0.5f * (p0[c * LDIM] + p0[c * LDIM + 1]);
            }
            if (q1 < NQ) {
#pragma unroll
                for (int c = 0; c < 32; ++c) z1[c] = 0.5f * (p1[c * LDIM] + p1[c * LDIM + 1]);
            }
        }
    }

    __syncthreads();

    // ---- scan: biased distance d' = e_sq - 2*dot (zz const per query);
    // dot chain order c=0..31 sequential (bit-identical to prior passing kernels).
    float bd0 = 3.4e38f, bd1 = 3.4e38f;
    int bv0 = 0, bv1 = 0;

#pragma unroll 2
    for (int v = 0; v < VC; ++v) {
        const float4* er = (const float4*)&e_ls[v * 32];
        float4 ea = er[0], eb = er[1], ec = er[2], ed = er[3];
        float4 ee = er[4], ef = er[5], eg = er[6], eh = er[7];
        float es = esq_ls[v];

        float d0, d1;
        {
            float a0 = z0[0] * ea.x, a1 = z1[0] * ea.x;
            a0 = fmaf(z0[1], ea.y, a0);  a1 = fmaf(z1[1], ea.y, a1);
            a0 = fmaf(z0[2], ea.z, a0);  a1 = fmaf(z1[2], ea.z, a1);
            a0 = fmaf(z0[3], ea.w, a0);  a1 = fmaf(z1[3], ea.w, a1);
            a0 = fmaf(z0[4], eb.x, a0);  a1 = fmaf(z1[4], eb.x, a1);
            a0 = fmaf(z0[5], eb.y, a0);  a1 = fmaf(z1[5], eb.y, a1);
            a0 = fmaf(z0[6], eb.z, a0);  a1 = fmaf(z1[6], eb.z, a1);
            a0 = fmaf(z0[7], eb.w, a0);  a1 = fmaf(z1[7], eb.w, a1);
            a0 = fmaf(z0[8], ec.x, a0);  a1 = fmaf(z1[8], ec.x, a1);
            a0 = fmaf(z0[9], ec.y, a0);  a1 = fmaf(z1[9], ec.y, a1);
            a0 = fmaf(z0[10], ec.z, a0); a1 = fmaf(z1[10], ec.z, a1);
            a0 = fmaf(z0[11], ec.w, a0); a1 = fmaf(z1[11], ec.w, a1);
            a0 = fmaf(z0[12], ed.x, a0); a1 = fmaf(z1[12], ed.x, a1);
            a0 = fmaf(z0[13], ed.y, a0); a1 = fmaf(z1[13], ed.y, a1);
            a0 = fmaf(z0[14], ed.z, a0); a1 = fmaf(z1[14], ed.z, a1);
            a0 = fmaf(z0[15], ed.w, a0); a1 = fmaf(z1[15], ed.w, a1);
            a0 = fmaf(z0[16], ee.x, a0); a1 = fmaf(z1[16], ee.x, a1);
            a0 = fmaf(z0[17], ee.y, a0); a1 = fmaf(z1[17], ee.y, a1);
            a0 = fmaf(z0[18], ee.z, a0); a1 = fmaf(z1[18], ee.z, a1);
            a0 = fmaf(z0[19], ee.w, a0); a1 = fmaf(z1[19], ee.w, a1);
            a0 = fmaf(z0[20], ef.x, a0); a1 = fmaf(z1[20], ef.x, a1);
            a0 = fmaf(z0[21], ef.y, a0); a1 = fmaf(z1[21], ef.y, a1);
            a0 = fmaf(z0[22], ef.z, a0); a1 = fmaf(z1[22], ef.z, a1);
            a0 = fmaf(z0[23], ef.w, a0); a1 = fmaf(z1[23], ef.w, a1);
            a0 = fmaf(z0[24], eg.x, a0); a1 = fmaf(z1[24], eg.x, a1);
            a0 = fmaf(z0[25], eg.y, a0); a1 = fmaf(z1[25], eg.y, a1);
            a0 = fmaf(z0[26], eg.z, a0); a1 = fmaf(z1[26], eg.z, a1);
            a0 = fmaf(z0[27], eg.w, a0); a1 = fmaf(z1[27], eg.w, a1);
            a0 = fmaf(z0[28], eh.x, a0); a1 = fmaf(z1[28], eh.x, a1);
            a0 = fmaf(z0[29], eh.y, a0); a1 = fmaf(z1[29], eh.y, a1);
            a0 = fmaf(z0[30], eh.z, a0); a1 = fmaf(z1[30], eh.z, a1);
            a0 = fmaf(z0[31], eh.w, a0); a1 = fmaf(z1[31], eh.w, a1);
            d0 = fmaf(a0, -2.0f, es);
            d1 = fmaf(a1, -2.0f, es);
        }
        int vg = vb + v;
        if (d0 < bd0) { bd0 = d0; bv0 = vg; }
        if (d1 < bd1) { bd1 = d1; bv1 = vg; }
    }

    if (q0 < NQ) {
        unsigned ud = __float_as_uint(bd0);
        ud = (ud & 0x80000000u) ? ~ud : (ud | 0x80000000u);
        atomicMin(&keys[q0], ((unsigned long long)ud << 32) | (unsigned)bv0);
    }
    if (q1 < NQ) {
        unsigned ud = __float_as_uint(bd1);
        ud = (ud & 0x80000000u) ? ~ud : (ud | 0x80000000u);
        atomicMin(&keys[q1], ((unsigned long long)ud << 32) | (unsigned)bv1);
    }
}

// ---------------------------------------------------------------- fused gather+upsample+phi+update+loss
// 64-element L-chunks (grid 16 x 32 = 512 blocks -> 2 blocks/CU instead of 1).
// Also: resets the NEXT scale's key buffer (ping-pong, disjoint from the one it reads),
// and for the last scale finalizes the loss via a done-counter.
__global__ __launch_bounds__(256) void fuse_kernel(
    const float* __restrict__ f, const float* __restrict__ emb,
    const unsigned long long* __restrict__ keys,
    unsigned long long* __restrict__ keys_next, int nq_next,
    const float* __restrict__ w, const float* __restrict__ bias,
    float* __restrict__ f_rest, float* __restrict__ f_hat,
    float* __restrict__ loss_acc, unsigned* __restrict__ done_ctr,
    float* __restrict__ out_loss, int pl)
{
    const int t  = threadIdx.x;
    const int b  = blockIdx.y;
    const int l0 = blockIdx.x * 64;

    // reset next scale's keys (different buffer than 'keys'; safe to do immediately)
    if (keys_next) {
        int x = (b * gridDim.x + blockIdx.x) * 256 + t;   // 512*256 = 131072 >= nq_next
        if (x < nq_next) keys_next[x] = ~0ull;
    }

    __shared__ float w_s[3072];      // [o][i][k]
    __shared__ float b_s[32];
    __shared__ float hs[32 * 68];    // [i][66 (+pad)] : col x -> l = l0 - 1 + x
    __shared__ float red[4];

    for (int x = t; x < 3072; x += 256) w_s[x] = w[x];
    if (t < 32) b_s[t] = bias[t];

    if (t < 66) {
        int l = l0 - 1 + t;
        if (l < 0 || l >= LDIM) {
#pragma unroll
            for (int i = 0; i < 32; ++i) hs[i * 68 + t] = 0.f;
        } else {
            int lo, hi; float wg;
            if (pl == LDIM) { lo = l; hi = l; wg = 0.f; }
            else {
                float pos = (l + 0.5f) * ((float)pl / 1024.0f) - 0.5f;
                pos = fminf(fmaxf(pos, 0.f), (float)(pl - 1));
                lo = (int)floorf(pos);
                hi = min(lo + 1, pl - 1);
                wg = pos - (float)lo;
            }
            int v0 = (int)(keys[b * pl + lo] & 0xFFFFFFFFull);
            int v1 = (int)(keys[b * pl + hi] & 0xFFFFFFFFull);
            const float4* e0 = (const float4*)(emb + (size_t)v0 * 32);
            const float4* e1 = (const float4*)(emb + (size_t)v1 * 32);
            float om = 1.0f - wg;
#pragma unroll
            for (int i4 = 0; i4 < 8; ++i4) {
                float4 a = e0[i4]; float4 c = e1[i4];
                hs[(i4*4+0) * 68 + t] = a.x * om + c.x * wg;
                hs[(i4*4+1) * 68 + t] = a.y * om + c.y * wg;
                hs[(i4*4+2) * 68 + t] = a.z * om + c.z * wg;
                hs[(i4*4+3) * 68 + t] = a.w * om + c.w * wg;
            }
        }
    }
    __syncthreads();

    const int o  = t >> 3;        // output channel, fixed per thread (w reuse x8)
    const int lg = t & 7;         // 8 consecutive l's per thread
    const float* wrow = &w_s[o * 96];
    float acc[8];
#pragma unroll
    for (int u = 0; u < 8; ++u) acc[u] = 0.f;
    const int hbase = lg * 8;     // hs col for l = l0 + lg*8 - 1

    for (int i = 0; i < 32; ++i) {
        float w0 = wrow[i * 3 + 0], w1 = wrow[i * 3 + 1], w2 = wrow[i * 3 + 2];
        const float* hrow = &hs[i * 68 + hbase];
        float hw[10];
#pragma unroll
        for (int x = 0; x < 10; ++x) hw[x] = hrow[x];
#pragma unroll
        for (int u = 0; u < 8; ++u) {
            acc[u] = fmaf(w0, hw[u], acc[u]);
            acc[u] = fmaf(w1, hw[u + 1], acc[u]);
            acc[u] = fmaf(w2, hw[u + 2], acc[u]);
        }
    }

    float lsum = 0.f;
    const int gbase = (b * 32 + o) * LDIM + l0 + lg * 8;
#pragma unroll
    for (int u = 0; u < 8; ++u) {
        float hval = hs[o * 68 + lg * 8 + 1 + u];
        float y = acc[u] + b_s[o];
        float ph = 0.5f * hval + 0.5f * y;    // h*(1-RESI) + (conv+b)*RESI, RESI=0.5
        int gi = gbase + u;
        float fh = f_hat[gi] + ph;
        f_hat[gi] = fh;
        f_rest[gi] -= ph;
        float df = fh - f[gi];
        lsum = fmaf(df, df, lsum);
    }

#pragma unroll
    for (int off = 32; off > 0; off >>= 1) lsum += __shfl_down(lsum, off, 64);
    if ((t & 63) == 0) red[t >> 6] = lsum;
    __syncthreads();
    if (t == 0) {
        atomicAdd(loss_acc, red[0] + red[1] + red[2] + red[3]);
        if (out_loss) {
            __threadfence();
            unsigned old = atomicAdd(done_ctr, 1u);
            if (old == (unsigned)(gridDim.x * gridDim.y - 1)) {
                float lv = atomicAdd(loss_acc, 0.0f);   // coherent read after all adds
                *out_loss = lv * (1.25f / (6.0f * (float)BCL));
            }
        }
    }
}

// ---------------------------------------------------------------- launch
extern "C" void kernel_launch(void* const* d_in, const int* in_sizes, int n_in,
                              void* d_out, int out_size, void* d_ws, size_t ws_size,
                              hipStream_t stream)
{
    const float* f    = (const float*)d_in[0];
    const float* emb  = (const float*)d_in[1];
    const float* phiw = (const float*)d_in[2];
    const float* phib = (const float*)d_in[3];

    float* f_hat    = (float*)d_out;        // BCL floats
    float* out_loss = f_hat + BCL;          // +1 float

    const int pls[6]  = {1, 4, 16, 64, 256, 1024};
    const int lpls[6] = {0, 2, 4, 6, 8, 10};
    // vchunks: grid fill vs atomic count. blocks = ceil(NQ/512) * vch.
    // pl=1024: 64*16 = 1024 blocks (4/CU, matches waves_per_eu(4)), VC=256.
    // pl=256: 16*32 = 512 blocks, VC=128. pl=64: 4*64 = 256 blocks, VC=64.
    const int vch[6]  = {64, 64, 64, 64, 32, 16};
    const int pidx[6] = {0, 0, 1, 2, 3, 3};          // PhiPartiallyShared static tick lookup

    char* ws = (char*)d_ws;
    float* f_rest             = (float*)ws;                            // 4 MB
    unsigned long long* keysA = (unsigned long long*)(ws + (size_t)BCL * 4);   // 256 KB

    // Ping-pong keys (A/B): fuse(si) reads one buffer and resets the other for si+1.
    // No hipMemsetAsync dispatches on the pp path. Fallback: single buffer + memsets.
    size_t need_pp = (size_t)BCL * 4 + (size_t)65536 * 8 + (size_t)VDIM * 4 + 64;
    bool pp = ws_size >= need_pp;
    unsigned long long* keysB = pp ? keysA + 32768 : keysA;
    size_t keys_bytes = pp ? (size_t)65536 * 8 : (size_t)32768 * 8;
    float* e_sq        = (float*)(ws + (size_t)BCL * 4 + keys_bytes);
    float* loss_acc    = e_sq + VDIM;
    unsigned* done_ctr = (unsigned*)(loss_acc + 1);

    init_kernel<<<dim3((BCL + 255) / 256), 256, 0, stream>>>(
        f, emb, f_rest, f_hat, e_sq, loss_acc, done_ctr, keysA, 32768);

    for (int si = 0; si < 6; ++si) {
        int pl = pls[si];
        int s  = LDIM / pl;
        int NQ = BDIM * pl;
        int qgroups = (NQ + 511) >> 9;
        int VC = VDIM / vch[si];
        unsigned long long* k  = (si & 1) ? keysB : keysA;
        unsigned long long* kn = (si < 5 && pp) ? ((si & 1) ? keysA : keysB) : nullptr;
        int nq_next = (si < 5) ? BDIM * pls[si + 1] : 0;
        if (!pp && si > 0) hipMemsetAsync(k, 0xFF, (size_t)NQ * 8, stream);
        vq_scan<<<dim3(qgroups * vch[si]), 256, 0, stream>>>(
            f_rest, emb, e_sq, k, lpls[si], s, NQ, VC, vch[si]);
        fuse_kernel<<<dim3(16, 32), 256, 0, stream>>>(
            f, emb, k, kn, nq_next,
            phiw + (size_t)pidx[si] * 3072, phib + (size_t)pidx[si] * 32,
            f_rest, f_hat, loss_acc, done_ctr,
            (si == 5) ? out_loss : nullptr, pl);
    }
}

// Round 10
// 422.752 us; speedup vs baseline: 1.1690x; 1.0478x over previous
//
#include <hip/hip_runtime.h>
#include <stdint.h>

#define BDIM 32
#define CDIM 32
#define LDIM 1024
#define VDIM 4096
#define BCL (BDIM*CDIM*LDIM)

// ---------------------------------------------------------------- init
__global__ void init_kernel(const float* __restrict__ f, const float* __restrict__ emb,
                            float* __restrict__ f_rest, float* __restrict__ f_hat,
                            float* __restrict__ e_sq, float* __restrict__ loss_acc,
                            unsigned* __restrict__ done_ctr,
                            unsigned long long* __restrict__ keys, int nkeys) {
    int i = blockIdx.x * blockDim.x + threadIdx.x;
    if (i < BCL) { f_rest[i] = f[i]; f_hat[i] = 0.0f; }
    if (i < VDIM) {
        const float4* e4 = (const float4*)(emb + (size_t)i * CDIM);
        float s = 0.f;
#pragma unroll
        for (int k = 0; k < 8; ++k) {
            float4 v = e4[k];
            s += v.x*v.x; s += v.y*v.y; s += v.z*v.z; s += v.w*v.w;
        }
        e_sq[i] = s;
    }
    if (i < nkeys) keys[i] = ~0ull;
    if (i == 0) { *loss_acc = 0.f; *done_ctr = 0u; }
}

// ---------------------------------------------------------------- VQ argmin: lane-per-query scan
// Structure (132us baseline): query PAIR per lane, code chunk in LDS read via wave-uniform
// broadcast ds_read_b128 (conflict-free), scalar argmin state, 2 atomicMin per lane at end.
// ROUND-10 changes:
//  - z_buf path: queries pre-downsampled by the PREVIOUS fuse into flat [NQ][32] ->
//    z-load = 8 coalesced float4 (kills 16x-redundant strided gathers; FETCH 16.7->~5MB).
//  - amdgpu_waves_per_eu(4,4): min AND max pinned (r9's (4) alone = min-only = reg CAP,
//    ignored by the heuristic which still targeted 8 waves/64 regs + AGPR parking).
__global__ __attribute__((amdgpu_waves_per_eu(4, 4))) __launch_bounds__(256) void vq_scan(
    const float* __restrict__ f_rest, const float* __restrict__ z_buf,
    const float* __restrict__ emb, const float* __restrict__ e_sq,
    unsigned long long* __restrict__ keys,
    int lpl, int s, int NQ, int VC, int vchunks)
{
    const int pl = 1 << lpl;
    const int t  = threadIdx.x;
    const int qg = blockIdx.x / vchunks;    // 512-query group
    const int vc = blockIdx.x % vchunks;
    const int vb = vc * VC;

    __shared__ __align__(16) float e_ls[256 * 32];   // up to 256 codes x 32 ch (32 KB)
    __shared__ float esq_ls[256];

    // ---- stage code chunk (linear, coalesced; VC*8 float4s over 256 threads)
    {
        const float4* src = (const float4*)emb + (size_t)vb * 8;
        float4* dst = (float4*)e_ls;
        for (int x = t; x < VC * 8; x += 256) dst[x] = src[x];
        for (int v = t; v < VC; v += 256) esq_ls[v] = e_sq[vb + v];
    }

    // ---- load this lane's two query vectors into registers
    const int lane = t & 63;
    const int wv   = t >> 6;
    const int q0 = qg * 512 + wv * 128 + lane;
    const int q1 = q0 + 64;
    const int qc0 = (q0 < NQ) ? q0 : NQ - 1;
    const int qc1 = (q1 < NQ) ? q1 : NQ - 1;

    float z0[32], z1[32];
    if (z_buf) {
        const float4* p0 = (const float4*)(z_buf + (size_t)qc0 * 32);
        const float4* p1 = (const float4*)(z_buf + (size_t)qc1 * 32);
#pragma unroll
        for (int c4 = 0; c4 < 8; ++c4) {
            float4 a = p0[c4], b = p1[c4];
            z0[c4*4+0] = a.x; z0[c4*4+1] = a.y; z0[c4*4+2] = a.z; z0[c4*4+3] = a.w;
            z1[c4*4+0] = b.x; z1[c4*4+1] = b.y; z1[c4*4+2] = b.z; z1[c4*4+3] = b.w;
        }
    } else {
        int b0 = qc0 >> lpl, j0 = qc0 & (pl - 1);
        int b1 = qc1 >> lpl, j1 = qc1 & (pl - 1);
        if (pl == LDIM) {
            const float* p0 = f_rest + b0 * (CDIM * LDIM) + j0;
            const float* p1 = f_rest + b1 * (CDIM * LDIM) + j1;
#pragma unroll
            for (int c = 0; c < 32; ++c) { z0[c] = p0[c * LDIM]; z1[c] = p1[c * LDIM]; }
        } else {
            int col0 = j0 * s + (s >> 1) - 1;
            int col1 = j1 * s + (s >> 1) - 1;
            const float* p0 = f_rest + b0 * (CDIM * LDIM) + col0;
            const float* p1 = f_rest + b1 * (CDIM * LDIM) + col1;
#pragma unroll
            for (int c = 0; c < 32; ++c) {
                z0[c] = 0.5f * (p0[c * LDIM] + p0[c * LDIM + 1]);
                z1[c] = 0.5f * (p1[c * LDIM] + p1[c * LDIM + 1]);
            }
        }
    }

    __syncthreads();

    // ---- scan: biased distance d' = e_sq - 2*dot (zz const per query);
    // dot chain order c=0..31 sequential (bit-identical to prior passing kernels).
    float bd0 = 3.4e38f, bd1 = 3.4e38f;
    int bv0 = 0, bv1 = 0;

#pragma unroll 2
    for (int v = 0; v < VC; ++v) {
        const float4* er = (const float4*)&e_ls[v * 32];
        float4 ea = er[0], eb = er[1], ec = er[2], ed = er[3];
        float4 ee = er[4], ef = er[5], eg = er[6], eh = er[7];
        float es = esq_ls[v];

        float d0, d1;
        {
            float a0 = z0[0] * ea.x, a1 = z1[0] * ea.x;
            a0 = fmaf(z0[1], ea.y, a0);  a1 = fmaf(z1[1], ea.y, a1);
            a0 = fmaf(z0[2], ea.z, a0);  a1 = fmaf(z1[2], ea.z, a1);
            a0 = fmaf(z0[3], ea.w, a0);  a1 = fmaf(z1[3], ea.w, a1);
            a0 = fmaf(z0[4], eb.x, a0);  a1 = fmaf(z1[4], eb.x, a1);
            a0 = fmaf(z0[5], eb.y, a0);  a1 = fmaf(z1[5], eb.y, a1);
            a0 = fmaf(z0[6], eb.z, a0);  a1 = fmaf(z1[6], eb.z, a1);
            a0 = fmaf(z0[7], eb.w, a0);  a1 = fmaf(z1[7], eb.w, a1);
            a0 = fmaf(z0[8], ec.x, a0);  a1 = fmaf(z1[8], ec.x, a1);
            a0 = fmaf(z0[9], ec.y, a0);  a1 = fmaf(z1[9], ec.y, a1);
            a0 = fmaf(z0[10], ec.z, a0); a1 = fmaf(z1[10], ec.z, a1);
            a0 = fmaf(z0[11], ec.w, a0); a1 = fmaf(z1[11], ec.w, a1);
            a0 = fmaf(z0[12], ed.x, a0); a1 = fmaf(z1[12], ed.x, a1);
            a0 = fmaf(z0[13], ed.y, a0); a1 = fmaf(z1[13], ed.y, a1);
            a0 = fmaf(z0[14], ed.z, a0); a1 = fmaf(z1[14], ed.z, a1);
            a0 = fmaf(z0[15], ed.w, a0); a1 = fmaf(z1[15], ed.w, a1);
            a0 = fmaf(z0[16], ee.x, a0); a1 = fmaf(z1[16], ee.x, a1);
            a0 = fmaf(z0[17], ee.y, a0); a1 = fmaf(z1[17], ee.y, a1);
            a0 = fmaf(z0[18], ee.z, a0); a1 = fmaf(z1[18], ee.z, a1);
            a0 = fmaf(z0[19], ee.w, a0); a1 = fmaf(z1[19], ee.w, a1);
            a0 = fmaf(z0[20], ef.x, a0); a1 = fmaf(z1[20], ef.x, a1);
            a0 = fmaf(z0[21], ef.y, a0); a1 = fmaf(z1[21], ef.y, a1);
            a0 = fmaf(z0[22], ef.z, a0); a1 = fmaf(z1[22], ef.z, a1);
            a0 = fmaf(z0[23], ef.w, a0); a1 = fmaf(z1[23], ef.w, a1);
            a0 = fmaf(z0[24], eg.x, a0); a1 = fmaf(z1[24], eg.x, a1);
            a0 = fmaf(z0[25], eg.y, a0); a1 = fmaf(z1[25], eg.y, a1);
            a0 = fmaf(z0[26], eg.z, a0); a1 = fmaf(z1[26], eg.z, a1);
            a0 = fmaf(z0[27], eg.w, a0); a1 = fmaf(z1[27], eg.w, a1);
            a0 = fmaf(z0[28], eh.x, a0); a1 = fmaf(z1[28], eh.x, a1);
            a0 = fmaf(z0[29], eh.y, a0); a1 = fmaf(z1[29], eh.y, a1);
            a0 = fmaf(z0[30], eh.z, a0); a1 = fmaf(z1[30], eh.z, a1);
            a0 = fmaf(z0[31], eh.w, a0); a1 = fmaf(z1[31], eh.w, a1);
            d0 = fmaf(a0, -2.0f, es);
            d1 = fmaf(a1, -2.0f, es);
        }
        int vg = vb + v;
        if (d0 < bd0) { bd0 = d0; bv0 = vg; }
        if (d1 < bd1) { bd1 = d1; bv1 = vg; }
    }

    if (q0 < NQ) {
        unsigned ud = __float_as_uint(bd0);
        ud = (ud & 0x80000000u) ? ~ud : (ud | 0x80000000u);
        atomicMin(&keys[q0], ((unsigned long long)ud << 32) | (unsigned)bv0);
    }
    if (q1 < NQ) {
        unsigned ud = __float_as_uint(bd1);
        ud = (ud & 0x80000000u) ? ~ud : (ud | 0x80000000u);
        atomicMin(&keys[q1], ((unsigned long long)ud << 32) | (unsigned)bv1);
    }
}

// ---------------------------------------------------------------- fused gather+upsample+phi+update+loss
// 64-element L-chunks (grid 16 x 32). Extras: resets next scale's key buffer (ping-pong);
// writes next scale's downsampled queries into z_buf (bit-identical 0.5*(fr[col]+fr[col+1]),
// via LDS since col+1 may belong to a neighboring thread); last scale finalizes the loss.
__global__ __launch_bounds__(256) void fuse_kernel(
    const float* __restrict__ f, const float* __restrict__ emb,
    const unsigned long long* __restrict__ keys,
    unsigned long long* __restrict__ keys_next, int nq_next,
    float* __restrict__ z_next, int s_next,
    const float* __restrict__ w, const float* __restrict__ bias,
    float* __restrict__ f_rest, float* __restrict__ f_hat,
    float* __restrict__ loss_acc, unsigned* __restrict__ done_ctr,
    float* __restrict__ out_loss, int pl)
{
    const int t  = threadIdx.x;
    const int b  = blockIdx.y;
    const int l0 = blockIdx.x * 64;

    // reset next scale's keys (different buffer than 'keys'; safe to do immediately)
    if (keys_next) {
        int x = (b * gridDim.x + blockIdx.x) * 256 + t;   // 512*256 = 131072 >= nq_next
        if (x < nq_next) keys_next[x] = ~0ull;
    }

    __shared__ float w_s[3072];      // [o][i][k]
    __shared__ float b_s[32];
    __shared__ float hs[32 * 68];    // [i][66 (+pad)] : col x -> l = l0 - 1 + x
    __shared__ float red[4];

    for (int x = t; x < 3072; x += 256) w_s[x] = w[x];
    if (t < 32) b_s[t] = bias[t];

    if (t < 66) {
        int l = l0 - 1 + t;
        if (l < 0 || l >= LDIM) {
#pragma unroll
            for (int i = 0; i < 32; ++i) hs[i * 68 + t] = 0.f;
        } else {
            int lo, hi; float wg;
            if (pl == LDIM) { lo = l; hi = l; wg = 0.f; }
            else {
                float pos = (l + 0.5f) * ((float)pl / 1024.0f) - 0.5f;
                pos = fminf(fmaxf(pos, 0.f), (float)(pl - 1));
                lo = (int)floorf(pos);
                hi = min(lo + 1, pl - 1);
                wg = pos - (float)lo;
            }
            int v0 = (int)(keys[b * pl + lo] & 0xFFFFFFFFull);
            int v1 = (int)(keys[b * pl + hi] & 0xFFFFFFFFull);
            const float4* e0 = (const float4*)(emb + (size_t)v0 * 32);
            const float4* e1 = (const float4*)(emb + (size_t)v1 * 32);
            float om = 1.0f - wg;
#pragma unroll
            for (int i4 = 0; i4 < 8; ++i4) {
                float4 a = e0[i4]; float4 c = e1[i4];
                hs[(i4*4+0) * 68 + t] = a.x * om + c.x * wg;
                hs[(i4*4+1) * 68 + t] = a.y * om + c.y * wg;
                hs[(i4*4+2) * 68 + t] = a.z * om + c.z * wg;
                hs[(i4*4+3) * 68 + t] = a.w * om + c.w * wg;
            }
        }
    }
    __syncthreads();

    const int o  = t >> 3;        // output channel, fixed per thread (w reuse x8)
    const int lg = t & 7;         // 8 consecutive l's per thread
    const float* wrow = &w_s[o * 96];
    float acc[8];
#pragma unroll
    for (int u = 0; u < 8; ++u) acc[u] = 0.f;
    const int hbase = lg * 8;     // hs col for l = l0 + lg*8 - 1

    for (int i = 0; i < 32; ++i) {
        float w0 = wrow[i * 3 + 0], w1 = wrow[i * 3 + 1], w2 = wrow[i * 3 + 2];
        const float* hrow = &hs[i * 68 + hbase];
        float hw[10];
#pragma unroll
        for (int x = 0; x < 10; ++x) hw[x] = hrow[x];
#pragma unroll
        for (int u = 0; u < 8; ++u) {
            acc[u] = fmaf(w0, hw[u], acc[u]);
            acc[u] = fmaf(w1, hw[u + 1], acc[u]);
            acc[u] = fmaf(w2, hw[u + 2], acc[u]);
        }
    }

    float lsum = 0.f;
    float frv[8];
    const int gbase = (b * 32 + o) * LDIM + l0 + lg * 8;
#pragma unroll
    for (int u = 0; u < 8; ++u) {
        float hval = hs[o * 68 + lg * 8 + 1 + u];
        float y = acc[u] + b_s[o];
        float ph = 0.5f * hval + 0.5f * y;    // h*(1-RESI) + (conv+b)*RESI, RESI=0.5
        int gi = gbase + u;
        float fh = f_hat[gi] + ph;
        f_hat[gi] = fh;
        float fr = f_rest[gi] - ph;
        f_rest[gi] = fr;
        frv[u] = fr;
        float df = fh - f[gi];
        lsum = fmaf(df, df, lsum);
    }

    // ---- write next scale's downsampled queries (z) from the fresh f_rest values.
    // s_next in {1,4,16,64}; col = j*s + s/2 - 1 stays inside [l0, l0+62] for s<=64.
    if (z_next) {
        __syncthreads();              // all hval reads done
#pragma unroll
        for (int u = 0; u < 8; ++u) hs[o * 68 + lg * 8 + u] = frv[u];   // [c][l-l0]
        __syncthreads();
        int npos = 64 / s_next;
        int qn_base = b * (LDIM / s_next) + l0 / s_next;
        for (int v = t; v < npos * 32; v += 256) {
            int jl = v >> 5, c = v & 31;
            float zv;
            if (s_next == 1) zv = hs[c * 68 + jl];
            else {
                int cl = jl * s_next + (s_next >> 1) - 1;
                zv = 0.5f * (hs[c * 68 + cl] + hs[c * 68 + cl + 1]);
            }
            z_next[(size_t)(qn_base + jl) * 32 + c] = zv;
        }
    }

#pragma unroll
    for (int off = 32; off > 0; off >>= 1) lsum += __shfl_down(lsum, off, 64);
    if ((t & 63) == 0) red[t >> 6] = lsum;
    __syncthreads();
    if (t == 0) {
        atomicAdd(loss_acc, red[0] + red[1] + red[2] + red[3]);
        if (out_loss) {
            __threadfence();
            unsigned old = atomicAdd(done_ctr, 1u);
            if (old == (unsigned)(gridDim.x * gridDim.y - 1)) {
                float lv = atomicAdd(loss_acc, 0.0f);   // coherent read after all adds
                *out_loss = lv * (1.25f / (6.0f * (float)BCL));
            }
        }
    }
}

// ---------------------------------------------------------------- launch
extern "C" void kernel_launch(void* const* d_in, const int* in_sizes, int n_in,
                              void* d_out, int out_size, void* d_ws, size_t ws_size,
                              hipStream_t stream)
{
    const float* f    = (const float*)d_in[0];
    const float* emb  = (const float*)d_in[1];
    const float* phiw = (const float*)d_in[2];
    const float* phib = (const float*)d_in[3];

    float* f_hat    = (float*)d_out;        // BCL floats
    float* out_loss = f_hat + BCL;          // +1 float

    const int pls[6]   = {1, 4, 16, 64, 256, 1024};
    const int lpls[6]  = {0, 2, 4, 6, 8, 10};
    const int vch[6]   = {64, 64, 64, 64, 32, 16};
    const int pidx[6]  = {0, 0, 1, 2, 3, 3};     // PhiPartiallyShared static tick lookup
    const int snx[6]   = {256, 64, 16, 4, 1, 0}; // s of scale si+1 (0 = none)

    char* ws = (char*)d_ws;
    float* f_rest             = (float*)ws;                            // 4 MB
    unsigned long long* keysA = (unsigned long long*)(ws + (size_t)BCL * 4);   // 256 KB

    // Layout: f_rest | keysA | (keysB) | (z_buf 4MB) | e_sq | loss | ctr
    size_t base = (size_t)BCL * 4;
    size_t need_pp   = base + (size_t)65536 * 8 + (size_t)VDIM * 4 + 64;
    size_t need_full = need_pp + (size_t)32768 * 32 * 4;
    bool pp   = ws_size >= need_pp;
    bool zb   = ws_size >= need_full;
    unsigned long long* keysB = pp ? keysA + 32768 : keysA;
    size_t keys_bytes = pp ? (size_t)65536 * 8 : (size_t)32768 * 8;
    float* z_buf = zb ? (float*)(ws + base + keys_bytes) : nullptr;
    size_t zoff  = zb ? (size_t)32768 * 32 * 4 : 0;
    float* e_sq        = (float*)(ws + base + keys_bytes + zoff);
    float* loss_acc    = e_sq + VDIM;
    unsigned* done_ctr = (unsigned*)(loss_acc + 1);

    init_kernel<<<dim3((BCL + 255) / 256), 256, 0, stream>>>(
        f, emb, f_rest, f_hat, e_sq, loss_acc, done_ctr, keysA, 32768);

    for (int si = 0; si < 6; ++si) {
        int pl = pls[si];
        int s  = LDIM / pl;
        int NQ = BDIM * pl;
        int qgroups = (NQ + 511) >> 9;
        int VC = VDIM / vch[si];
        unsigned long long* k  = (si & 1) ? keysB : keysA;
        unsigned long long* kn = (si < 5 && pp) ? ((si & 1) ? keysA : keysB) : nullptr;
        int nq_next = (si < 5) ? BDIM * pls[si + 1] : 0;
        if (!pp && si > 0) hipMemsetAsync(k, 0xFF, (size_t)NQ * 8, stream);
        const float* zread = (zb && si >= 2) ? z_buf : nullptr;
        float* zwrite      = (zb && si >= 1 && si <= 4) ? z_buf : nullptr;
        vq_scan<<<dim3(qgroups * vch[si]), 256, 0, stream>>>(
            f_rest, zread, emb, e_sq, k, lpls[si], s, NQ, VC, vch[si]);
        fuse_kernel<<<dim3(16, 32), 256, 0, stream>>>(
            f, emb, k, kn, nq_next, zwrite, snx[si],
            phiw + (size_t)pidx[si] * 3072, phib + (size_t)pidx[si] * 32,
            f_rest, f_hat, loss_acc, done_ctr,
            (si == 5) ? out_loss : nullptr, pl);
    }
}

// Round 11
// 416.808 us; speedup vs baseline: 1.1856x; 1.0143x over previous
//
#include <hip/hip_runtime.h>
#include <stdint.h>

#define BDIM 32
#define CDIM 32
#define LDIM 1024
#define VDIM 4096
#define BCL (BDIM*CDIM*LDIM)

// ---------------------------------------------------------------- init
__global__ void init_kernel(const float* __restrict__ f, const float* __restrict__ emb,
                            float* __restrict__ f_rest, float* __restrict__ f_hat,
                            float* __restrict__ e_sq, float* __restrict__ loss_acc,
                            unsigned* __restrict__ done_ctr,
                            unsigned long long* __restrict__ keys, int nkeys) {
    int i = blockIdx.x * blockDim.x + threadIdx.x;
    if (i < BCL) { f_rest[i] = f[i]; f_hat[i] = 0.0f; }
    if (i < VDIM) {
        const float4* e4 = (const float4*)(emb + (size_t)i * CDIM);
        float s = 0.f;
#pragma unroll
        for (int k = 0; k < 8; ++k) {
            float4 v = e4[k];
            s += v.x*v.x; s += v.y*v.y; s += v.z*v.z; s += v.w*v.w;
        }
        e_sq[i] = s;
    }
    if (i < nkeys) keys[i] = ~0ull;
    if (i == 0) { *loss_acc = 0.f; *done_ctr = 0u; }
}

// ---------------------------------------------------------------- VQ argmin: lane-per-query scan
// ROUND-11: 1 query x 2 codes per iteration (transposed from 2q x 1code).
// Rationale: VGPR_Count=64 for 3 rounds straight -- the allocator pins this kernel shape
// at a 64-arch-VGPR target and parks overflow in AGPRs (v_accvgpr_read per FMA operand =
// ~2x VALU issue). All waves_per_eu knobs proved inert. Fix BY CONSTRUCTION: per-lane
// demand = z[32] + streaming e (~16) + misc (~10) ~= 58 < 64 -> no AGPR parking possible.
// Dual interleaved dot chains (codes v,v+1) keep FMA-latency-hiding ILP. Code chunk in
// LDS read via wave-uniform broadcast ds_read_b128 (conflict-free, 16B/read/wave -> LDS
// stays >10x under VALU). Dot chain c=0..31 sequential, strict < with ascending v:
// bit-identical results + first-index tie-break. 2 atomicMin per lane-pair... 1 per lane.
__global__ __launch_bounds__(256) void vq_scan(
    const float* __restrict__ f_rest, const float* __restrict__ z_buf,
    const float* __restrict__ emb, const float* __restrict__ e_sq,
    unsigned long long* __restrict__ keys,
    int lpl, int s, int NQ, int VC, int vchunks)
{
    const int pl = 1 << lpl;
    const int t  = threadIdx.x;
    const int qg = blockIdx.x / vchunks;    // 256-query group
    const int vc = blockIdx.x % vchunks;
    const int vb = vc * VC;

    __shared__ __align__(16) float e_ls[256 * 32];   // up to 256 codes x 32 ch (32 KB)
    __shared__ float esq_ls[256];

    // ---- stage code chunk (linear, coalesced; VC*8 float4s over 256 threads)
    {
        const float4* src = (const float4*)emb + (size_t)vb * 8;
        float4* dst = (float4*)e_ls;
        for (int x = t; x < VC * 8; x += 256) dst[x] = src[x];
        for (int v = t; v < VC; v += 256) esq_ls[v] = e_sq[vb + v];
    }

    // ---- load this lane's query vector into registers
    const int q  = qg * 256 + t;
    const int qc = (q < NQ) ? q : NQ - 1;

    float z[32];
    if (z_buf) {
        const float4* p = (const float4*)(z_buf + (size_t)qc * 32);
#pragma unroll
        for (int c4 = 0; c4 < 8; ++c4) {
            float4 a = p[c4];
            z[c4*4+0] = a.x; z[c4*4+1] = a.y; z[c4*4+2] = a.z; z[c4*4+3] = a.w;
        }
    } else {
        int b0 = qc >> lpl, j0 = qc & (pl - 1);
        if (pl == LDIM) {
            const float* p = f_rest + b0 * (CDIM * LDIM) + j0;
#pragma unroll
            for (int c = 0; c < 32; ++c) z[c] = p[c * LDIM];
        } else {
            int col = j0 * s + (s >> 1) - 1;
            const float* p = f_rest + b0 * (CDIM * LDIM) + col;
#pragma unroll
            for (int c = 0; c < 32; ++c) z[c] = 0.5f * (p[c * LDIM] + p[c * LDIM + 1]);
        }
    }

    __syncthreads();

    // ---- scan: biased distance d' = e_sq - 2*dot (zz const per query);
    // dual chains over codes v and v+1; chain order c=0..31 (bit-identical).
    float bd = 3.4e38f;
    int bv = 0;

#pragma unroll 1
    for (int v = 0; v < VC; v += 2) {
        const float4* er0 = (const float4*)&e_ls[(size_t)v * 32];
        const float4* er1 = (const float4*)&e_ls[(size_t)(v + 1) * 32];
        float es0 = esq_ls[v];
        float es1 = esq_ls[v + 1];

        float4 p0 = er0[0], p1 = er1[0];
        float a0 = z[0] * p0.x,            a1 = z[0] * p1.x;
        a0 = fmaf(z[1], p0.y, a0);         a1 = fmaf(z[1], p1.y, a1);
        a0 = fmaf(z[2], p0.z, a0);         a1 = fmaf(z[2], p1.z, a1);
        a0 = fmaf(z[3], p0.w, a0);         a1 = fmaf(z[3], p1.w, a1);
#pragma unroll
        for (int c4 = 1; c4 < 8; ++c4) {
            p0 = er0[c4]; p1 = er1[c4];
            a0 = fmaf(z[c4*4+0], p0.x, a0);  a1 = fmaf(z[c4*4+0], p1.x, a1);
            a0 = fmaf(z[c4*4+1], p0.y, a0);  a1 = fmaf(z[c4*4+1], p1.y, a1);
            a0 = fmaf(z[c4*4+2], p0.z, a0);  a1 = fmaf(z[c4*4+2], p1.z, a1);
            a0 = fmaf(z[c4*4+3], p0.w, a0);  a1 = fmaf(z[c4*4+3], p1.w, a1);
        }
        float d0 = fmaf(a0, -2.0f, es0);
        float d1 = fmaf(a1, -2.0f, es1);
        if (d0 < bd) { bd = d0; bv = vb + v; }
        if (d1 < bd) { bd = d1; bv = vb + v + 1; }
    }

    if (q < NQ) {
        unsigned ud = __float_as_uint(bd);
        ud = (ud & 0x80000000u) ? ~ud : (ud | 0x80000000u);
        atomicMin(&keys[q], ((unsigned long long)ud << 32) | (unsigned)bv);
    }
}

// ---------------------------------------------------------------- fused gather+upsample+phi+update+loss
// 64-element L-chunks (grid 16 x 32). Extras: resets next scale's key buffer (ping-pong);
// writes next scale's downsampled queries into z_buf (bit-identical 0.5*(fr[col]+fr[col+1]),
// via LDS since col+1 may belong to a neighboring thread); last scale finalizes the loss.
__global__ __launch_bounds__(256) void fuse_kernel(
    const float* __restrict__ f, const float* __restrict__ emb,
    const unsigned long long* __restrict__ keys,
    unsigned long long* __restrict__ keys_next, int nq_next,
    float* __restrict__ z_next, int s_next,
    const float* __restrict__ w, const float* __restrict__ bias,
    float* __restrict__ f_rest, float* __restrict__ f_hat,
    float* __restrict__ loss_acc, unsigned* __restrict__ done_ctr,
    float* __restrict__ out_loss, int pl)
{
    const int t  = threadIdx.x;
    const int b  = blockIdx.y;
    const int l0 = blockIdx.x * 64;

    // reset next scale's keys (different buffer than 'keys'; safe to do immediately)
    if (keys_next) {
        int x = (b * gridDim.x + blockIdx.x) * 256 + t;   // 512*256 = 131072 >= nq_next
        if (x < nq_next) keys_next[x] = ~0ull;
    }

    __shared__ float w_s[3072];      // [o][i][k]
    __shared__ float b_s[32];
    __shared__ float hs[32 * 68];    // [i][66 (+pad)] : col x -> l = l0 - 1 + x
    __shared__ float red[4];

    for (int x = t; x < 3072; x += 256) w_s[x] = w[x];
    if (t < 32) b_s[t] = bias[t];

    if (t < 66) {
        int l = l0 - 1 + t;
        if (l < 0 || l >= LDIM) {
#pragma unroll
            for (int i = 0; i < 32; ++i) hs[i * 68 + t] = 0.f;
        } else {
            int lo, hi; float wg;
            if (pl == LDIM) { lo = l; hi = l; wg = 0.f; }
            else {
                float pos = (l + 0.5f) * ((float)pl / 1024.0f) - 0.5f;
                pos = fminf(fmaxf(pos, 0.f), (float)(pl - 1));
                lo = (int)floorf(pos);
                hi = min(lo + 1, pl - 1);
                wg = pos - (float)lo;
            }
            int v0 = (int)(keys[b * pl + lo] & 0xFFFFFFFFull);
            int v1 = (int)(keys[b * pl + hi] & 0xFFFFFFFFull);
            const float4* e0 = (const float4*)(emb + (size_t)v0 * 32);
            const float4* e1 = (const float4*)(emb + (size_t)v1 * 32);
            float om = 1.0f - wg;
#pragma unroll
            for (int i4 = 0; i4 < 8; ++i4) {
                float4 a = e0[i4]; float4 c = e1[i4];
                hs[(i4*4+0) * 68 + t] = a.x * om + c.x * wg;
                hs[(i4*4+1) * 68 + t] = a.y * om + c.y * wg;
                hs[(i4*4+2) * 68 + t] = a.z * om + c.z * wg;
                hs[(i4*4+3) * 68 + t] = a.w * om + c.w * wg;
            }
        }
    }
    __syncthreads();

    const int o  = t >> 3;        // output channel, fixed per thread (w reuse x8)
    const int lg = t & 7;         // 8 consecutive l's per thread
    const float* wrow = &w_s[o * 96];
    float acc[8];
#pragma unroll
    for (int u = 0; u < 8; ++u) acc[u] = 0.f;
    const int hbase = lg * 8;     // hs col for l = l0 + lg*8 - 1

    for (int i = 0; i < 32; ++i) {
        float w0 = wrow[i * 3 + 0], w1 = wrow[i * 3 + 1], w2 = wrow[i * 3 + 2];
        const float* hrow = &hs[i * 68 + hbase];
        float hw[10];
#pragma unroll
        for (int x = 0; x < 10; ++x) hw[x] = hrow[x];
#pragma unroll
        for (int u = 0; u < 8; ++u) {
            acc[u] = fmaf(w0, hw[u], acc[u]);
            acc[u] = fmaf(w1, hw[u + 1], acc[u]);
            acc[u] = fmaf(w2, hw[u + 2], acc[u]);
        }
    }

    float lsum = 0.f;
    float frv[8];
    const int gbase = (b * 32 + o) * LDIM + l0 + lg * 8;
#pragma unroll
    for (int u = 0; u < 8; ++u) {
        float hval = hs[o * 68 + lg * 8 + 1 + u];
        float y = acc[u] + b_s[o];
        float ph = 0.5f * hval + 0.5f * y;    // h*(1-RESI) + (conv+b)*RESI, RESI=0.5
        int gi = gbase + u;
        float fh = f_hat[gi] + ph;
        f_hat[gi] = fh;
        float fr = f_rest[gi] - ph;
        f_rest[gi] = fr;
        frv[u] = fr;
        float df = fh - f[gi];
        lsum = fmaf(df, df, lsum);
    }

    // ---- write next scale's downsampled queries (z) from the fresh f_rest values.
    // s_next in {1,4,16,64}; col = j*s + s/2 - 1 stays inside [l0, l0+62] for s<=64.
    if (z_next) {
        __syncthreads();              // all hval reads done
#pragma unroll
        for (int u = 0; u < 8; ++u) hs[o * 68 + lg * 8 + u] = frv[u];   // [c][l-l0]
        __syncthreads();
        int npos = 64 / s_next;
        int qn_base = b * (LDIM / s_next) + l0 / s_next;
        for (int v = t; v < npos * 32; v += 256) {
            int jl = v >> 5, c = v & 31;
            float zv;
            if (s_next == 1) zv = hs[c * 68 + jl];
            else {
                int cl = jl * s_next + (s_next >> 1) - 1;
                zv = 0.5f * (hs[c * 68 + cl] + hs[c * 68 + cl + 1]);
            }
            z_next[(size_t)(qn_base + jl) * 32 + c] = zv;
        }
    }

#pragma unroll
    for (int off = 32; off > 0; off >>= 1) lsum += __shfl_down(lsum, off, 64);
    if ((t & 63) == 0) red[t >> 6] = lsum;
    __syncthreads();
    if (t == 0) {
        atomicAdd(loss_acc, red[0] + red[1] + red[2] + red[3]);
        if (out_loss) {
            __threadfence();
            unsigned old = atomicAdd(done_ctr, 1u);
            if (old == (unsigned)(gridDim.x * gridDim.y - 1)) {
                float lv = atomicAdd(loss_acc, 0.0f);   // coherent read after all adds
                *out_loss = lv * (1.25f / (6.0f * (float)BCL));
            }
        }
    }
}

// ---------------------------------------------------------------- launch
extern "C" void kernel_launch(void* const* d_in, const int* in_sizes, int n_in,
                              void* d_out, int out_size, void* d_ws, size_t ws_size,
                              hipStream_t stream)
{
    const float* f    = (const float*)d_in[0];
    const float* emb  = (const float*)d_in[1];
    const float* phiw = (const float*)d_in[2];
    const float* phib = (const float*)d_in[3];

    float* f_hat    = (float*)d_out;        // BCL floats
    float* out_loss = f_hat + BCL;          // +1 float

    const int pls[6]   = {1, 4, 16, 64, 256, 1024};
    const int lpls[6]  = {0, 2, 4, 6, 8, 10};
    const int vch[6]   = {64, 64, 64, 64, 32, 16};
    const int pidx[6]  = {0, 0, 1, 2, 3, 3};     // PhiPartiallyShared static tick lookup
    const int snx[6]   = {256, 64, 16, 4, 1, 0}; // s of scale si+1 (0 = none)

    char* ws = (char*)d_ws;
    float* f_rest             = (float*)ws;                            // 4 MB
    unsigned long long* keysA = (unsigned long long*)(ws + (size_t)BCL * 4);   // 256 KB

    // Layout: f_rest | keysA | (keysB) | (z_buf 4MB) | e_sq | loss | ctr
    size_t base = (size_t)BCL * 4;
    size_t need_pp   = base + (size_t)65536 * 8 + (size_t)VDIM * 4 + 64;
    size_t need_full = need_pp + (size_t)32768 * 32 * 4;
    bool pp   = ws_size >= need_pp;
    bool zb   = ws_size >= need_full;
    unsigned long long* keysB = pp ? keysA + 32768 : keysA;
    size_t keys_bytes = pp ? (size_t)65536 * 8 : (size_t)32768 * 8;
    float* z_buf = zb ? (float*)(ws + base + keys_bytes) : nullptr;
    size_t zoff  = zb ? (size_t)32768 * 32 * 4 : 0;
    float* e_sq        = (float*)(ws + base + keys_bytes + zoff);
    float* loss_acc    = e_sq + VDIM;
    unsigned* done_ctr = (unsigned*)(loss_acc + 1);

    init_kernel<<<dim3((BCL + 255) / 256), 256, 0, stream>>>(
        f, emb, f_rest, f_hat, e_sq, loss_acc, done_ctr, keysA, 32768);

    for (int si = 0; si < 6; ++si) {
        int pl = pls[si];
        int s  = LDIM / pl;
        int NQ = BDIM * pl;
        int qgroups = (NQ + 255) >> 8;
        int VC = VDIM / vch[si];
        unsigned long long* k  = (si & 1) ? keysB : keysA;
        unsigned long long* kn = (si < 5 && pp) ? ((si & 1) ? keysA : keysB) : nullptr;
        int nq_next = (si < 5) ? BDIM * pls[si + 1] : 0;
        if (!pp && si > 0) hipMemsetAsync(k, 0xFF, (size_t)NQ * 8, stream);
        const float* zread = (zb && si >= 2) ? z_buf : nullptr;
        float* zwrite      = (zb && si >= 1 && si <= 4) ? z_buf : nullptr;
        vq_scan<<<dim3(qgroups * vch[si]), 256, 0, stream>>>(
            f_rest, zread, emb, e_sq, k, lpls[si], s, NQ, VC, vch[si]);
        fuse_kernel<<<dim3(16, 32), 256, 0, stream>>>(
            f, emb, k, kn, nq_next, zwrite, snx[si],
            phiw + (size_t)pidx[si] * 3072, phib + (size_t)pidx[si] * 32,
            f_rest, f_hat, loss_acc, done_ctr,
            (si == 5) ? out_loss : nullptr, pl);
    }
}